// Round 6
// baseline (98.960 us; speedup 1.0000x reference)
//
#include <hip/hip_runtime.h>

// VOCAB=1e6, DIM=64, BAGS=16384, N_IDX=819200, CAT_DIM=128.
// Output row = [eb(64) | eb(64) | cat(128)] = 256 f32.
//
// R6: 4-bit repack pipeline. Codes are 0..15 in int32 (256B/row, 32B of info).
//  1) init+mark: init output, flag referenced vocab rows (1MB bytes in ws).
//  2) repack: referenced rows only (~56%) -> 8 dwords/row (8 nibbles each).
//     Monotonic read ~143MB (streaming-with-gaps) instead of 188MB random.
//  3) gather: R4 structure, row load = ONE broadcast dword (32B/row) from the
//     L2/L3-resident packed table. Flushes stay wave-coalesced 256B atomics.
// Everything in d_ws is recomputed every call (no cross-call state).

constexpr int CHUNK = 50;
constexpr int GROUP = 25;

__device__ __forceinline__ float readlane_f(float x, int k) {
    return __int_as_float(__builtin_amdgcn_readlane(__float_as_int(x), k));
}

__device__ __forceinline__ int detect_sh(const unsigned int* p) {
    // int64 vs int32 layout (LE): high words of first 4 indices == 0.
    return ((p[1] | p[3] | p[5] | p[7]) == 0u) ? 1 : 0;
}

// Fused: init output (cols 0..127 zero, 128..255 = cat) + mark referenced rows.
__global__ __launch_bounds__(256) void init_mark_kernel(
    const float* __restrict__ cat, float* __restrict__ out,
    const unsigned int* __restrict__ idx32,
    unsigned char* __restrict__ flags, int n_mark, int total)
{
    const int t = blockIdx.x * 256 + threadIdx.x;
    if (t < total) {
        const int b = t >> 8, c = t & 255;
        out[t] = (c < 128) ? 0.0f : cat[(b << 7) + (c - 128)];
    }
    if (t < n_mark) {
        const int sh = detect_sh(idx32);
        flags[idx32[(unsigned)t << sh]] = 1;
    }
}

// Pack 64 int32 codes -> 8 dwords per referenced row.
// Wave handles 8 rows: lane = subrow(3b) | part(3b); dword `part` of a row
// holds dims 8*part .. 8*part+7 (nibble j = dim 8*part+j).
__global__ __launch_bounds__(256) void repack_kernel(
    const int* __restrict__ wq, const unsigned char* __restrict__ flags,
    unsigned int* __restrict__ packed, int vocab)
{
    const int lane = threadIdx.x & 63;
    const int wid  = blockIdx.x * 4 + (threadIdx.x >> 6);
    const int row  = wid * 8 + (lane >> 3);
    const int part = lane & 7;
    if (row >= vocab) return;           // vocab % 8 == 0 -> wave-uniform
    if (!flags[row]) return;            // skip fetch of unreferenced rows
    const int* src = wq + (long long)row * 64 + part * 8;
    const int4 q0 = *(const int4*)(src);
    const int4 q1 = *(const int4*)(src + 4);
    const unsigned int p =
          (unsigned)(q0.x & 15)        | ((unsigned)(q0.y & 15) << 4)
        | ((unsigned)(q0.z & 15) << 8) | ((unsigned)(q0.w & 15) << 12)
        | ((unsigned)(q1.x & 15) << 16)| ((unsigned)(q1.y & 15) << 20)
        | ((unsigned)(q1.z & 15) << 24)| ((unsigned)(q1.w & 15) << 28);
    packed[(long long)row * 8 + part] = p;
}

// Gather on packed table (R4 structure: CHUNK=50 per wave, burst GROUP=25).
__global__ __launch_bounds__(256) void embag_packed_kernel(
    const unsigned int* __restrict__ packed,
    const float* __restrict__ scales,
    const float* __restrict__ biases,
    const unsigned int* __restrict__ idx32,
    const unsigned int* __restrict__ off32,
    float* __restrict__ out, int num_bags, int n_idx)
{
    const int sh = detect_sh(idx32);
    const int lane = threadIdx.x & 63;
    const int wid  = blockIdx.x * 4 + (threadIdx.x >> 6);
    const long long base = (long long)wid * CHUNK;
    if (base >= n_idx) return;
    const int i0  = (int)base;
    const int cnt = min(CHUNK, n_idx - i0);

    const int li = i0 + min(lane, cnt - 1);
    const int myidx = (int)idx32[(unsigned)li << sh];
    const float mys = scales[myidx];
    const float myb = biases[myidx];

    int lo = 0, hi = num_bags - 1;
    while (lo < hi) {
        int mid = (lo + hi) >> 1;
        if ((int)off32[(unsigned)(mid + 1) << sh] > i0) hi = mid; else lo = mid + 1;
    }
    int b = lo;
    int bend = (int)off32[(unsigned)(b + 1) << sh];

    float acc = 0.f, ab = 0.f;
    const int word = lane >> 3;               // dword of the row I read
    const unsigned int nsh = (lane & 7) * 4;  // my nibble within it (dim = lane)

    for (int g = 0; g < CHUNK; g += GROUP) {
        unsigned int q[GROUP];
        #pragma unroll
        for (int k = 0; k < GROUP; ++k) {
            const int ik = __builtin_amdgcn_readlane(myidx, g + k); // SGPR
            q[k] = packed[((long long)(unsigned)ik << 3) + word];   // 32B bcast
        }
        #pragma unroll
        for (int k = 0; k < GROUP; ++k) {
            const int j = i0 + g + k;
            if (j >= n_idx) break;
            if (j >= bend) {
                const float v = acc + ab;
                float* p = out + ((long long)b << 8) + lane;
                atomicAdd(p, v);
                atomicAdd(p + 64, v);
                acc = 0.f; ab = 0.f;
                do { ++b; bend = (int)off32[(unsigned)(b + 1) << sh]; } while (bend <= j);
            }
            const float c = (float)((q[k] >> nsh) & 15u);
            acc = fmaf(c, readlane_f(mys, g + k), acc);
            ab += readlane_f(myb, g + k);
        }
    }
    const float v = acc + ab;
    float* p = out + ((long long)b << 8) + lane;
    atomicAdd(p, v);
    atomicAdd(p + 64, v);
}

// Fallback (R4): direct gather on the raw table when ws is too small.
__global__ __launch_bounds__(256) void embag_kernel(
    const int* __restrict__ wq,
    const float* __restrict__ scales,
    const float* __restrict__ biases,
    const unsigned int* __restrict__ idx32,
    const unsigned int* __restrict__ off32,
    float* __restrict__ out, int num_bags, int n_idx)
{
    const int sh = detect_sh(idx32);
    const int lane = threadIdx.x & 63;
    const int wid  = blockIdx.x * 4 + (threadIdx.x >> 6);
    const long long base = (long long)wid * CHUNK;
    if (base >= n_idx) return;
    const int i0  = (int)base;
    const int cnt = min(CHUNK, n_idx - i0);

    const int li = i0 + min(lane, cnt - 1);
    const int myidx = (int)idx32[(unsigned)li << sh];
    const float mys = scales[myidx];
    const float myb = biases[myidx];

    int lo = 0, hi = num_bags - 1;
    while (lo < hi) {
        int mid = (lo + hi) >> 1;
        if ((int)off32[(unsigned)(mid + 1) << sh] > i0) hi = mid; else lo = mid + 1;
    }
    int b = lo;
    int bend = (int)off32[(unsigned)(b + 1) << sh];

    float acc = 0.f, ab = 0.f;
    const char* wqb = (const char*)wq + (lane << 2);

    for (int g = 0; g < CHUNK; g += GROUP) {
        int q[GROUP];
        #pragma unroll
        for (int k = 0; k < GROUP; ++k) {
            const int ik = __builtin_amdgcn_readlane(myidx, g + k);
            q[k] = *(const int*)(wqb + ((long long)ik << 8));
        }
        #pragma unroll
        for (int k = 0; k < GROUP; ++k) {
            const int j = i0 + g + k;
            if (j >= n_idx) break;
            if (j >= bend) {
                const float v = acc + ab;
                float* p = out + ((long long)b << 8) + lane;
                atomicAdd(p, v);
                atomicAdd(p + 64, v);
                acc = 0.f; ab = 0.f;
                do { ++b; bend = (int)off32[(unsigned)(b + 1) << sh]; } while (bend <= j);
            }
            acc = fmaf((float)q[k], readlane_f(mys, g + k), acc);
            ab += readlane_f(myb, g + k);
        }
    }
    const float v = acc + ab;
    float* p = out + ((long long)b << 8) + lane;
    atomicAdd(p, v);
    atomicAdd(p + 64, v);
}

extern "C" void kernel_launch(void* const* d_in, const int* in_sizes, int n_in,
                              void* d_out, int out_size, void* d_ws, size_t ws_size,
                              hipStream_t stream) {
    const int*          wq     = (const int*)d_in[0];
    const float*        scales = (const float*)d_in[1];
    const float*        biases = (const float*)d_in[2];
    const unsigned int* idx32  = (const unsigned int*)d_in[3];
    const unsigned int* off32  = (const unsigned int*)d_in[4];
    const float*        cat    = (const float*)d_in[5];
    float*              out    = (float*)d_out;

    const int num_bags = in_sizes[5] / 128;       // 16384
    const int n_idx    = in_sizes[3];             // 819200
    const int vocab    = in_sizes[1];             // 1e6
    const int total    = num_bags * 256;

    const size_t flagsz = ((size_t)vocab + 4095) & ~(size_t)4095;
    const size_t need   = flagsz + (size_t)vocab * 32;

    const int nchunks = (n_idx + CHUNK - 1) / CHUNK;   // 16384 waves
    const int gblocks = (nchunks + 3) / 4;             // 4096

    if (ws_size >= need) {
        unsigned char* flags  = (unsigned char*)d_ws;
        unsigned int*  packed = (unsigned int*)((char*)d_ws + flagsz);

        hipMemsetAsync(flags, 0, (size_t)vocab, stream);

        const int imax = (total > n_idx) ? total : n_idx;
        init_mark_kernel<<<(imax + 255) / 256, 256, 0, stream>>>(
            cat, out, idx32, flags, n_idx, total);

        const int rwaves  = (vocab + 7) / 8;           // 125000
        const int rblocks = (rwaves + 3) / 4;          // 31250
        repack_kernel<<<rblocks, 256, 0, stream>>>(wq, flags, packed, vocab);

        embag_packed_kernel<<<gblocks, 256, 0, stream>>>(
            packed, scales, biases, idx32, off32, out, num_bags, n_idx);
    } else {
        init_mark_kernel<<<(total + 255) / 256, 256, 0, stream>>>(
            cat, out, idx32, (unsigned char*)d_ws, 0, total);
        embag_kernel<<<gblocks, 256, 0, stream>>>(
            wq, scales, biases, idx32, off32, out, num_bags, n_idx);
    }
}